// Round 8
// baseline (618.807 us; speedup 1.0000x reference)
//
#include <hip/hip_runtime.h>
#include <math.h>

typedef float f4 __attribute__((ext_vector_type(4)));
typedef __attribute__((ext_vector_type(8)))  __bf16 bf16x8;
typedef __attribute__((ext_vector_type(16))) float  f32x16;
typedef __attribute__((ext_vector_type(4)))  unsigned short us4;

// Problem constants: B=16, C=D=256, H=W=64 -> S=4096 spatial/batch, N=65536 rows, K=1024 codes.
#define GAP_TAU 0.05f

// float -> bf16 round-to-nearest-even
__device__ __forceinline__ unsigned short f2bf(float f) {
    unsigned int u = __float_as_uint(f);
    return (unsigned short)((u + 0x7fffu + ((u >> 16) & 1u)) >> 16);
}

// ===========================================================================
// numpy-fp32 pairwise-sum replication helpers (baseline-SIMD SSE order).
// ===========================================================================
__device__ __forceinline__ float np_half128(const float* s) {
    float r[8][4];
    #pragma unroll
    for (int j = 0; j < 8; ++j)
        #pragma unroll
        for (int l = 0; l < 4; ++l) r[j][l] = s[j * 4 + l];
    #pragma unroll
    for (int m = 1; m < 4; ++m)
        #pragma unroll
        for (int j = 0; j < 8; ++j)
            #pragma unroll
            for (int l = 0; l < 4; ++l)
                r[j][l] = __fadd_rn(r[j][l], s[m * 32 + j * 4 + l]);
    float c[4];
    #pragma unroll
    for (int l = 0; l < 4; ++l) {
        float t01 = __fadd_rn(r[0][l], r[1][l]);
        float t23 = __fadd_rn(r[2][l], r[3][l]);
        float t45 = __fadd_rn(r[4][l], r[5][l]);
        float t67 = __fadd_rn(r[6][l], r[7][l]);
        c[l] = __fadd_rn(__fadd_rn(t01, t23), __fadd_rn(t45, t67));
    }
    return __fadd_rn(__fadd_rn(c[0], c[1]), __fadd_rn(c[2], c[3]));
}
__device__ __forceinline__ float np_sum256(const float* s) {
    return __fadd_rn(np_half128(s), np_half128(s + 128));
}

// ---------------------------------------------------------------------------
// K0: c2s[k] = (float)( sum_d codebook[k][d]^2 (fp64) - 256.0 )  [fast path]
// ---------------------------------------------------------------------------
__global__ __launch_bounds__(256) void k_c2(const float* __restrict__ cb,
                                            float* __restrict__ c2s) {
    int k = blockIdx.x * 256 + threadIdx.x;
    if (k >= 1024) return;
    const float* row = cb + (size_t)k * 256;
    double s = 0.0;
    for (int d = 0; d < 256; ++d) { double v = (double)row[d]; s += v * v; }
    c2s[k] = (float)(s - 256.0);
}

// ---------------------------------------------------------------------------
// K0b: split codebook into bf16 hi/lo planes, TRANSPOSED granule layout:
// granule (chunk = d>>3, code k) at f4-index chunk*1024 + k; elems j = d&7.
// Makes 32-code tile staging coalesced and B-frag ds_reads lane-contiguous.
// ---------------------------------------------------------------------------
__global__ __launch_bounds__(256) void k_pack(const float* __restrict__ cb,
                                              unsigned short* __restrict__ eh,
                                              unsigned short* __restrict__ el) {
    int i = blockIdx.x * 256 + threadIdx.x;   // grid 1024 -> 262144 elems
    int k = i >> 8, d = i & 255;
    float v = cb[i];
    unsigned short h = f2bf(v);
    float hf = __uint_as_float((unsigned int)h << 16);
    int o = (((d >> 3) << 10) + k) * 8 + (d & 7);
    eh[o] = h;
    el[o] = f2bf(v - hf);
}

// ---------------------------------------------------------------------------
// K1: 1x1 conv (channel-mix GEMM) + fused L2 row-normalize.
// Emits normalized features as bf16 hi/lo planes [n][256] (row-major).
// ---------------------------------------------------------------------------
__global__ __launch_bounds__(256) void k_conv(const float* __restrict__ x,
                                              const float* __restrict__ w,
                                              const float* __restrict__ bias,
                                              unsigned short* __restrict__ fh,
                                              unsigned short* __restrict__ fl) {
    __shared__ f4 xs4[32 * 16];   // [kk][p/4]
    __shared__ f4 ws4[32 * 64];   // [kk][o/4]
    float* wsf = (float*)ws4;

    const int t  = threadIdx.x;
    const int og = t & 15;
    const int pg = t >> 4;
    const int b  = blockIdx.x >> 6;
    const int s0 = (blockIdx.x & 63) << 6;

    const f4* x4    = (const f4*)(x + ((size_t)b * 256) * 4096 + s0);
    const f4* w4row = (const f4*)(w + (size_t)t * 256);

    float acc[4][16];
    #pragma unroll
    for (int p = 0; p < 4; ++p)
        #pragma unroll
        for (int u = 0; u < 16; ++u) acc[p][u] = 0.f;

    for (int c0 = 0; c0 < 256; c0 += 32) {
        __syncthreads();
        #pragma unroll
        for (int j = 0; j < 2; ++j) {
            int lin = t + j * 256;
            int kk = lin >> 4, p4 = lin & 15;
            xs4[kk * 16 + p4] = x4[(size_t)(c0 + kk) * 1024 + p4];
        }
        {
            f4 wv[8];
            #pragma unroll
            for (int j = 0; j < 8; ++j) wv[j] = w4row[(c0 >> 2) + j];
            #pragma unroll
            for (int j = 0; j < 8; ++j)
                #pragma unroll
                for (int i = 0; i < 4; ++i)
                    wsf[(j * 4 + i) * 256 + t] = wv[j][i];
        }
        __syncthreads();
        #pragma unroll 8
        for (int kk = 0; kk < 32; ++kk) {
            f4 xv = xs4[kk * 16 + pg];
            f4 wv[4];
            wv[0] = ws4[kk * 64 + og];
            wv[1] = ws4[kk * 64 + og + 16];
            wv[2] = ws4[kk * 64 + og + 32];
            wv[3] = ws4[kk * 64 + og + 48];
            #pragma unroll
            for (int p = 0; p < 4; ++p)
                #pragma unroll
                for (int u = 0; u < 4; ++u)
                    #pragma unroll
                    for (int i = 0; i < 4; ++i)
                        acc[p][u * 4 + i] += xv[p] * wv[u][i];
        }
    }

    f4 bv[4];
    #pragma unroll
    for (int u = 0; u < 4; ++u) bv[u] = ((const f4*)bias)[og + 16 * u];

    const size_t n0 = (size_t)b * 4096 + s0;
    us4* fh4 = (us4*)fh;
    us4* fl4 = (us4*)fl;
    #pragma unroll
    for (int p = 0; p < 4; ++p) {
        f4 q[4];
        float n2 = 0.f;
        #pragma unroll
        for (int u = 0; u < 4; ++u)
            #pragma unroll
            for (int i = 0; i < 4; ++i) {
                float qv = acc[p][u * 4 + i] + bv[u][i];
                q[u][i] = qv;
                n2 += qv * qv;
            }
        #pragma unroll
        for (int m = 1; m <= 8; m <<= 1) n2 += __shfl_xor(n2, m, 64);
        float norm = fmaxf(sqrtf(n2), 1e-12f);
        float inv = 1.0f / norm;
        #pragma unroll
        for (int u = 0; u < 4; ++u) {
            us4 sh, sl;
            #pragma unroll
            for (int i = 0; i < 4; ++i) {
                float v = q[u][i] * inv;
                unsigned short h = f2bf(v);
                sh[i] = h;
                sl[i] = f2bf(v - __uint_as_float((unsigned int)h << 16));
            }
            size_t o8 = (n0 + pg * 4 + p) * 64 + og + 16 * u;
            fh4[o8] = sh;
            fl4[o8] = sl;
        }
    }
}

// ---------------------------------------------------------------------------
// K2: distance argmin via bf16-split MFMA, LDS-staged E tiles.
// Block: 512 thr / 8 waves; block tile = 256 pos; wave = 32 pos, A (F hi/lo)
// resident in registers. Loop over 32 code-tiles (32 codes): stage E-tile
// (hi+lo, 32 KB) into LDS via reg-staging (issue next loads under compute).
// dot ~ fh*eh + fh*el + fl*eh (error ~1e-4 << GAP_TAU). Score = c2s - 2*dot.
// ---------------------------------------------------------------------------
__global__ __launch_bounds__(512, 2) void k_dist(const unsigned short* __restrict__ fh_g,
                                                 const unsigned short* __restrict__ fl_g,
                                                 const unsigned short* __restrict__ eh_t,
                                                 const unsigned short* __restrict__ el_t,
                                                 const float* __restrict__ c2s,
                                                 int* __restrict__ idxout,
                                                 int* __restrict__ flagcnt,
                                                 int* __restrict__ flaglist) {
    __shared__ f4 ebuf[2048];     // [plane][chunk 0..31][code-local 0..31] granules, 32 KB

    const int t   = threadIdx.x;
    const int w   = t >> 6;
    const int l   = t & 63;
    const int col = l & 31;
    const int g   = l >> 5;
    const int n0  = blockIdx.x * 256;
    const int row = n0 + w * 32 + col;

    // A fragments resident: 16 k-steps x (hi, lo)
    bf16x8 ah[16], al[16];
    {
        const f4* fhr = (const f4*)fh_g + (size_t)row * 32;
        const f4* flr = (const f4*)fl_g + (size_t)row * 32;
        #pragma unroll
        for (int s = 0; s < 16; ++s) {
            ah[s] = __builtin_bit_cast(bf16x8, fhr[s * 2 + g]);
            al[s] = __builtin_bit_cast(bf16x8, flr[s * 2 + g]);
        }
    }

    // staging thread -> granule mapping (granule gi = chunk*32 + c within tile)
    const int sc0 = t & 31;       // code-local
    const int sh0 = t >> 5;       // chunk for gi = t
    const f4* ehp = (const f4*)eh_t;
    const f4* elp = (const f4*)el_t;

    float best[16], best2[16]; int bidx[16];
    #pragma unroll
    for (int r = 0; r < 16; ++r) { best[r] = 3.4e38f; best2[r] = 3.4e38f; bidx[r] = 0; }

    f4 rga[4], rgb[4];
    // prologue: load tile 0
    rga[0] = ehp[sh0 * 1024 + sc0];
    rga[1] = ehp[(sh0 + 16) * 1024 + sc0];
    rga[2] = elp[sh0 * 1024 + sc0];
    rga[3] = elp[(sh0 + 16) * 1024 + sc0];

    for (int ct = 0; ct < 32; ++ct) {
        const f4* cur = (ct & 1) ? rgb : rga;
        f4*       nxt = (ct & 1) ? rga : rgb;
        __syncthreads();                       // prev tile's readers done
        ebuf[t]         = cur[0];
        ebuf[t + 512]   = cur[1];
        ebuf[t + 1024]  = cur[2];
        ebuf[t + 1536]  = cur[3];
        if (ct + 1 < 32) {                     // issue next-tile loads (hidden under compute)
            int kb = (ct + 1) * 32;
            nxt[0] = ehp[sh0 * 1024 + kb + sc0];
            nxt[1] = ehp[(sh0 + 16) * 1024 + kb + sc0];
            nxt[2] = elp[sh0 * 1024 + kb + sc0];
            nxt[3] = elp[(sh0 + 16) * 1024 + kb + sc0];
        }
        __syncthreads();                       // ds_writes visible

        f32x16 acc;
        #pragma unroll
        for (int r = 0; r < 16; ++r) acc[r] = 0.f;
        #pragma unroll
        for (int s = 0; s < 16; ++s) {
            int chunk = s * 2 + g;
            bf16x8 bh = __builtin_bit_cast(bf16x8, ebuf[chunk * 32 + col]);
            bf16x8 bl = __builtin_bit_cast(bf16x8, ebuf[1024 + chunk * 32 + col]);
            acc = __builtin_amdgcn_mfma_f32_32x32x16_bf16(ah[s], bh, acc, 0, 0, 0);
            acc = __builtin_amdgcn_mfma_f32_32x32x16_bf16(ah[s], bl, acc, 0, 0, 0);
            acc = __builtin_amdgcn_mfma_f32_32x32x16_bf16(al[s], bh, acc, 0, 0, 0);
        }

        const int code = ct * 32 + col;
        const float c2 = c2s[code];
        #pragma unroll
        for (int r = 0; r < 16; ++r) {
            float sc = fmaf(-2.0f, acc[r], c2);
            if (sc < best[r]) { best2[r] = best[r]; best[r] = sc; bidx[r] = code; }
            else if (sc < best2[r]) { best2[r] = sc; }
        }
    }

    // cross-lane top-2 merge over the 32 code columns (g kept separate: rows differ)
    #pragma unroll
    for (int m = 1; m <= 16; m <<= 1) {
        #pragma unroll
        for (int r = 0; r < 16; ++r) {
            float ov  = __shfl_xor(best[r],  m, 64);
            int   oi  = __shfl_xor(bidx[r],  m, 64);
            float ov2 = __shfl_xor(best2[r], m, 64);
            bool owin = (ov < best[r]) || (ov == best[r] && oi < bidx[r]);
            float loser = owin ? best[r] : ov;
            best2[r] = fminf(fminf(best2[r], ov2), loser);
            if (owin) { best[r] = ov; bidx[r] = oi; }
        }
    }
    if (col == 0) {
        #pragma unroll
        for (int r = 0; r < 16; ++r) {
            int pos = (r & 3) + 8 * (r >> 2) + 4 * g;
            int n = n0 + w * 32 + pos;
            idxout[n] = bidx[r];
            if (best2[r] - best[r] < GAP_TAU) {
                int slot = atomicAdd(flagcnt, 1);
                if (slot < 65536) flaglist[slot] = n;
            }
        }
    }
}

// ---------------------------------------------------------------------------
// K2b: refine flagged rows, replicating the numpy-fp32 reference pipeline.
// (unchanged from the passing rounds)
// ---------------------------------------------------------------------------
__global__ __launch_bounds__(256) void k_refine(const float* __restrict__ x,
                                                const float* __restrict__ w,
                                                const float* __restrict__ bias,
                                                const float* __restrict__ cb,
                                                const int* __restrict__ flaglist,
                                                const int* __restrict__ flagcnt,
                                                int* __restrict__ idxout) {
    __shared__ float xs[256];
    __shared__ float flat[256];
    __shared__ float fn[256];
    __shared__ float sq[256];
    __shared__ float sv[256];
    __shared__ int   si[256];
    __shared__ float bc[2];
    const int t = threadIdx.x;
    int cnt = *flagcnt;
    if (cnt > 65536) cnt = 65536;

    for (int r = blockIdx.x; r < cnt; r += gridDim.x) {
        const int n = flaglist[r];
        const int b = n >> 12, s = n & 4095;
        xs[t] = x[((size_t)b * 256 + t) * 4096 + s];
        __syncthreads();
        {
            const f4* xv4 = (const f4*)xs;
            const f4* wv4 = (const f4*)(w + (size_t)t * 256);
            float a0 = 0.f, a1 = 0.f, a2 = 0.f, a3 = 0.f;
            for (int c4 = 0; c4 < 64; ++c4) {
                f4 xv = xv4[c4];
                f4 wv = wv4[c4];
                a0 = __fadd_rn(a0, __fmul_rn(xv[0], wv[0]));
                a1 = __fadd_rn(a1, __fmul_rn(xv[1], wv[1]));
                a2 = __fadd_rn(a2, __fmul_rn(xv[2], wv[2]));
                a3 = __fadd_rn(a3, __fmul_rn(xv[3], wv[3]));
            }
            float q = __fadd_rn(__fadd_rn(a0, a1), __fadd_rn(a2, a3));
            flat[t] = __fadd_rn(q, bias[t]);
        }
        sq[t] = __fmul_rn(flat[t], flat[t]);
        __syncthreads();
        if (t == 0) bc[0] = fmaxf(__fsqrt_rn(np_sum256(sq)), 1e-12f);
        __syncthreads();
        fn[t] = __fdiv_rn(flat[t], bc[0]);
        __syncthreads();
        sq[t] = __fmul_rn(fn[t], fn[t]);
        __syncthreads();
        if (t == 0) bc[1] = np_sum256(sq);
        __syncthreads();
        const float t1f = bc[1];

        float best = 3.4e38f; int bi = 0x7fffffff;
        #pragma unroll 1
        for (int kq = 0; kq < 4; ++kq) {
            int k = kq * 256 + t;
            const f4* e4 = (const f4*)(cb + (size_t)k * 256);
            double dot = 0.0;
            float hres[2];
            #pragma unroll 1
            for (int h = 0; h < 2; ++h) {
                float rr[8][4];
                #pragma unroll
                for (int j = 0; j < 8; ++j)
                    #pragma unroll
                    for (int l = 0; l < 4; ++l) rr[j][l] = 0.f;
                #pragma unroll 1
                for (int m = 0; m < 4; ++m) {
                    #pragma unroll
                    for (int j = 0; j < 8; ++j) {
                        f4 v = e4[h * 32 + m * 8 + j];
                        #pragma unroll
                        for (int l = 0; l < 4; ++l) {
                            dot += (double)fn[h * 128 + m * 32 + j * 4 + l] * (double)v[l];
                            rr[j][l] = __fadd_rn(rr[j][l], __fmul_rn(v[l], v[l]));
                        }
                    }
                }
                float c[4];
                #pragma unroll
                for (int l = 0; l < 4; ++l) {
                    float t01 = __fadd_rn(rr[0][l], rr[1][l]);
                    float t23 = __fadd_rn(rr[2][l], rr[3][l]);
                    float t45 = __fadd_rn(rr[4][l], rr[5][l]);
                    float t67 = __fadd_rn(rr[6][l], rr[7][l]);
                    c[l] = __fadd_rn(__fadd_rn(t01, t23), __fadd_rn(t45, t67));
                }
                hres[h] = __fadd_rn(__fadd_rn(c[0], c[1]), __fadd_rn(c[2], c[3]));
            }
            float e2f = __fadd_rn(hres[0], hres[1]);
            float gf  = (float)(2.0 * dot);
            float d2  = __fadd_rn(__fsub_rn(t1f, gf), e2f);
            if (d2 < best) { best = d2; bi = k; }
        }
        sv[t] = best; si[t] = bi;
        __syncthreads();
        for (int off = 128; off > 0; off >>= 1) {
            if (t < off) {
                if (sv[t + off] < sv[t] || (sv[t + off] == sv[t] && si[t + off] < si[t])) {
                    sv[t] = sv[t + off]; si[t] = si[t + off];
                }
            }
            __syncthreads();
        }
        if (t == 0) idxout[n] = si[0];
        __syncthreads();
    }
}

// ---------------------------------------------------------------------------
// K3: gather + NHWC->NCHW write.
// ---------------------------------------------------------------------------
__global__ __launch_bounds__(256) void k_gather(const int* __restrict__ idx,
                                                const float* __restrict__ cb,
                                                float* __restrict__ out) {
    const int t = threadIdx.x;
    const int b = blockIdx.x >> 4;
    const int s = ((blockIdx.x & 15) << 8) + t;
    const int n = b * 4096 + s;
    const int k = idx[n];
    const f4* row = (const f4*)(cb + (size_t)k * 256);
    float* ob = out + (size_t)b * 256 * 4096 + s;
    #pragma unroll 8
    for (int d4 = 0; d4 < 64; ++d4) {
        f4 v = row[d4];
        ob[(size_t)(d4 * 4 + 0) * 4096] = v[0];
        ob[(size_t)(d4 * 4 + 1) * 4096] = v[1];
        ob[(size_t)(d4 * 4 + 2) * 4096] = v[2];
        ob[(size_t)(d4 * 4 + 3) * 4096] = v[3];
    }
}

// ---------------------------------------------------------------------------
extern "C" void kernel_launch(void* const* d_in, const int* in_sizes, int n_in,
                              void* d_out, int out_size, void* d_ws, size_t ws_size,
                              hipStream_t stream) {
    const float* x    = (const float*)d_in[0];
    const float* w    = (const float*)d_in[1];
    const float* bias = (const float*)d_in[2];
    const float* cb   = (const float*)d_in[3];
    float* out = (float*)d_out;

    char* ws = (char*)d_ws;
    unsigned short* fh    = (unsigned short*)ws;                  // 33554432 B
    unsigned short* fl    = (unsigned short*)(ws + 33554432);     // 33554432 B
    int*            idx   = (int*)(ws + 67108864);                //   262144 B
    float*          c2s   = (float*)(ws + 67371008);              //     4096 B
    int*            fcnt  = (int*)(ws + 67375104);                //      256 B
    int*            flist = (int*)(ws + 67375360);                //   262144 B
    unsigned short* eh    = (unsigned short*)(ws + 67637504);     //   524288 B (transposed granules)
    unsigned short* el    = (unsigned short*)(ws + 68161792);     //   524288 B

    hipMemsetAsync(fcnt, 0, 4, stream);
    k_c2    <<<4,    256, 0, stream>>>(cb, c2s);
    k_pack  <<<1024, 256, 0, stream>>>(cb, eh, el);
    k_conv  <<<1024, 256, 0, stream>>>(x, w, bias, fh, fl);
    k_dist  <<<256,  512, 0, stream>>>(fh, fl, eh, el, c2s, idx, fcnt, flist);
    k_refine<<<256,  256, 0, stream>>>(x, w, bias, cb, flist, fcnt, idx);
    k_gather<<<256,  256, 0, stream>>>(idx, cb, out);
}

// Round 9
// 524.810 us; speedup vs baseline: 1.1791x; 1.1791x over previous
//
#include <hip/hip_runtime.h>
#include <math.h>

typedef float f4 __attribute__((ext_vector_type(4)));
typedef __attribute__((ext_vector_type(8)))  __bf16 bf16x8;
typedef __attribute__((ext_vector_type(16))) float  f32x16;
typedef __attribute__((ext_vector_type(4)))  unsigned short us4;

// Problem constants: B=16, C=D=256, H=W=64 -> S=4096 spatial/batch, N=65536 rows, K=1024 codes.
#define GAP_TAU 0.05f

// float -> bf16 round-to-nearest-even
__device__ __forceinline__ unsigned short f2bf(float f) {
    unsigned int u = __float_as_uint(f);
    return (unsigned short)((u + 0x7fffu + ((u >> 16) & 1u)) >> 16);
}

// ===========================================================================
// numpy-fp32 pairwise-sum replication helpers (baseline-SIMD SSE order).
// ===========================================================================
__device__ __forceinline__ float np_half128(const float* s) {
    float r[8][4];
    #pragma unroll
    for (int j = 0; j < 8; ++j)
        #pragma unroll
        for (int l = 0; l < 4; ++l) r[j][l] = s[j * 4 + l];
    #pragma unroll
    for (int m = 1; m < 4; ++m)
        #pragma unroll
        for (int j = 0; j < 8; ++j)
            #pragma unroll
            for (int l = 0; l < 4; ++l)
                r[j][l] = __fadd_rn(r[j][l], s[m * 32 + j * 4 + l]);
    float c[4];
    #pragma unroll
    for (int l = 0; l < 4; ++l) {
        float t01 = __fadd_rn(r[0][l], r[1][l]);
        float t23 = __fadd_rn(r[2][l], r[3][l]);
        float t45 = __fadd_rn(r[4][l], r[5][l]);
        float t67 = __fadd_rn(r[6][l], r[7][l]);
        c[l] = __fadd_rn(__fadd_rn(t01, t23), __fadd_rn(t45, t67));
    }
    return __fadd_rn(__fadd_rn(c[0], c[1]), __fadd_rn(c[2], c[3]));
}
__device__ __forceinline__ float np_sum256(const float* s) {
    return __fadd_rn(np_half128(s), np_half128(s + 128));
}

// ---------------------------------------------------------------------------
// K0: c2s[k] = (float)( sum_d codebook[k][d]^2 (fp64) - 256.0 )  [fast path]
// ---------------------------------------------------------------------------
__global__ __launch_bounds__(256) void k_c2(const float* __restrict__ cb,
                                            float* __restrict__ c2s) {
    int k = blockIdx.x * 256 + threadIdx.x;
    if (k >= 1024) return;
    const float* row = cb + (size_t)k * 256;
    double s = 0.0;
    for (int d = 0; d < 256; ++d) { double v = (double)row[d]; s += v * v; }
    c2s[k] = (float)(s - 256.0);
}

// ---------------------------------------------------------------------------
// K0b: split codebook into bf16 hi/lo planes, TRANSPOSED granule layout:
// granule (chunk = d>>3, code k) at f4-index chunk*1024 + k; elems j = d&7.
// ---------------------------------------------------------------------------
__global__ __launch_bounds__(256) void k_pack(const float* __restrict__ cb,
                                              unsigned short* __restrict__ eh,
                                              unsigned short* __restrict__ el) {
    int i = blockIdx.x * 256 + threadIdx.x;   // grid 1024 -> 262144 elems
    int k = i >> 8, d = i & 255;
    float v = cb[i];
    unsigned short h = f2bf(v);
    float hf = __uint_as_float((unsigned int)h << 16);
    int o = (((d >> 3) << 10) + k) * 8 + (d & 7);
    eh[o] = h;
    el[o] = f2bf(v - hf);
}

// ---------------------------------------------------------------------------
// K1: 1x1 conv (channel-mix GEMM) + fused L2 row-normalize.
// Emits normalized features as bf16 hi/lo planes [n][256] (row-major).
// ---------------------------------------------------------------------------
__global__ __launch_bounds__(256) void k_conv(const float* __restrict__ x,
                                              const float* __restrict__ w,
                                              const float* __restrict__ bias,
                                              unsigned short* __restrict__ fh,
                                              unsigned short* __restrict__ fl) {
    __shared__ f4 xs4[32 * 16];   // [kk][p/4]
    __shared__ f4 ws4[32 * 64];   // [kk][o/4]
    float* wsf = (float*)ws4;

    const int t  = threadIdx.x;
    const int og = t & 15;
    const int pg = t >> 4;
    const int b  = blockIdx.x >> 6;
    const int s0 = (blockIdx.x & 63) << 6;

    const f4* x4    = (const f4*)(x + ((size_t)b * 256) * 4096 + s0);
    const f4* w4row = (const f4*)(w + (size_t)t * 256);

    float acc[4][16];
    #pragma unroll
    for (int p = 0; p < 4; ++p)
        #pragma unroll
        for (int u = 0; u < 16; ++u) acc[p][u] = 0.f;

    for (int c0 = 0; c0 < 256; c0 += 32) {
        __syncthreads();
        #pragma unroll
        for (int j = 0; j < 2; ++j) {
            int lin = t + j * 256;
            int kk = lin >> 4, p4 = lin & 15;
            xs4[kk * 16 + p4] = x4[(size_t)(c0 + kk) * 1024 + p4];
        }
        {
            f4 wv[8];
            #pragma unroll
            for (int j = 0; j < 8; ++j) wv[j] = w4row[(c0 >> 2) + j];
            #pragma unroll
            for (int j = 0; j < 8; ++j)
                #pragma unroll
                for (int i = 0; i < 4; ++i)
                    wsf[(j * 4 + i) * 256 + t] = wv[j][i];
        }
        __syncthreads();
        #pragma unroll 8
        for (int kk = 0; kk < 32; ++kk) {
            f4 xv = xs4[kk * 16 + pg];
            f4 wv[4];
            wv[0] = ws4[kk * 64 + og];
            wv[1] = ws4[kk * 64 + og + 16];
            wv[2] = ws4[kk * 64 + og + 32];
            wv[3] = ws4[kk * 64 + og + 48];
            #pragma unroll
            for (int p = 0; p < 4; ++p)
                #pragma unroll
                for (int u = 0; u < 4; ++u)
                    #pragma unroll
                    for (int i = 0; i < 4; ++i)
                        acc[p][u * 4 + i] += xv[p] * wv[u][i];
        }
    }

    f4 bv[4];
    #pragma unroll
    for (int u = 0; u < 4; ++u) bv[u] = ((const f4*)bias)[og + 16 * u];

    const size_t n0 = (size_t)b * 4096 + s0;
    us4* fh4 = (us4*)fh;
    us4* fl4 = (us4*)fl;
    #pragma unroll
    for (int p = 0; p < 4; ++p) {
        f4 q[4];
        float n2 = 0.f;
        #pragma unroll
        for (int u = 0; u < 4; ++u)
            #pragma unroll
            for (int i = 0; i < 4; ++i) {
                float qv = acc[p][u * 4 + i] + bv[u][i];
                q[u][i] = qv;
                n2 += qv * qv;
            }
        #pragma unroll
        for (int m = 1; m <= 8; m <<= 1) n2 += __shfl_xor(n2, m, 64);
        float norm = fmaxf(sqrtf(n2), 1e-12f);
        float inv = 1.0f / norm;
        #pragma unroll
        for (int u = 0; u < 4; ++u) {
            us4 sh, sl;
            #pragma unroll
            for (int i = 0; i < 4; ++i) {
                float v = q[u][i] * inv;
                unsigned short h = f2bf(v);
                sh[i] = h;
                sl[i] = f2bf(v - __uint_as_float((unsigned int)h << 16));
            }
            size_t o8 = (n0 + pg * 4 + p) * 64 + og + 16 * u;
            fh4[o8] = sh;
            fl4[o8] = sl;
        }
    }
}

// ---------------------------------------------------------------------------
// K2: distance argmin via bf16-split MFMA; E tiles staged with
// global_load_lds into double-buffered LDS (no staging VGPRs -> no spill).
// Block: 512 thr / 8 waves; block tile = 256 pos; wave = 32 pos, A (F hi/lo)
// resident in registers (128 VGPR). 32 code-tiles of 32 codes.
// dot ~ fh*eh + fh*el + fl*eh (error ~1e-4 << GAP_TAU). Score = c2s - 2*dot.
// ---------------------------------------------------------------------------
__global__ __launch_bounds__(512, 2) void k_dist(const unsigned short* __restrict__ fh_g,
                                                 const unsigned short* __restrict__ fl_g,
                                                 const unsigned short* __restrict__ eh_t,
                                                 const unsigned short* __restrict__ el_t,
                                                 const float* __restrict__ c2s,
                                                 int* __restrict__ idxout,
                                                 int* __restrict__ flagcnt,
                                                 int* __restrict__ flaglist) {
    __shared__ f4 ebuf[2][2048];   // [buf][plane*1024 + chunk*32 + code] granules, 2 x 32 KB

    const int t   = threadIdx.x;
    const int w   = t >> 6;
    const int l   = t & 63;
    const int col = l & 31;
    const int g   = l >> 5;
    const int n0  = blockIdx.x * 256;
    const int row = n0 + w * 32 + col;

    // A fragments resident: 16 k-steps x (hi, lo)
    bf16x8 ah[16], al[16];
    {
        const f4* fhr = (const f4*)fh_g + (size_t)row * 32;
        const f4* flr = (const f4*)fl_g + (size_t)row * 32;
        #pragma unroll
        for (int s = 0; s < 16; ++s) {
            ah[s] = __builtin_bit_cast(bf16x8, fhr[s * 2 + g]);
            al[s] = __builtin_bit_cast(bf16x8, flr[s * 2 + g]);
        }
    }

    // staging geometry: lane l of wave w, issue j covers LDS granule
    // gidx = w*256 + j*64 + l (linear dest); global source per-lane.
    const f4* ehp = (const f4*)eh_t;
    const f4* elp = (const f4*)el_t;
    const int gbase = w * 256 + l;              // + j*64
    // per-j constants (plane/chunk/code-local of this lane's granule)
    int src_off[4]; const f4* src_base[4];
    #pragma unroll
    for (int j = 0; j < 4; ++j) {
        int gidx = gbase + j * 64;
        int plane = gidx >> 10, rem = gidx & 1023;
        src_base[j] = plane ? elp : ehp;
        src_off[j]  = (rem >> 5) * 1024 + (rem & 31);   // + kb
    }

    float best[16], best2[16]; int bidx[16];
    #pragma unroll
    for (int r = 0; r < 16; ++r) { best[r] = 3.4e38f; best2[r] = 3.4e38f; bidx[r] = 0; }

    // prologue: stage tile 0 into ebuf[0]
    #pragma unroll
    for (int j = 0; j < 4; ++j) {
        __builtin_amdgcn_global_load_lds(
            (const __attribute__((address_space(1))) unsigned int*)(src_base[j] + src_off[j]),
            (__attribute__((address_space(3))) unsigned int*)&ebuf[0][w * 256 + j * 64],
            16, 0, 0);
    }
    asm volatile("s_waitcnt vmcnt(0)" ::: "memory");
    __syncthreads();

    int cur = 0;
    for (int ct = 0; ct < 32; ++ct) {
        // issue next tile's staging first (hidden under this tile's compute)
        if (ct + 1 < 32) {
            int kb = (ct + 1) * 32;
            #pragma unroll
            for (int j = 0; j < 4; ++j) {
                __builtin_amdgcn_global_load_lds(
                    (const __attribute__((address_space(1))) unsigned int*)(src_base[j] + src_off[j] + kb),
                    (__attribute__((address_space(3))) unsigned int*)&ebuf[cur ^ 1][w * 256 + j * 64],
                    16, 0, 0);
            }
        }

        const f4* eb = &ebuf[cur][0];
        f32x16 acc;
        #pragma unroll
        for (int r = 0; r < 16; ++r) acc[r] = 0.f;
        #pragma unroll
        for (int s = 0; s < 16; ++s) {
            int chunk = s * 2 + g;
            bf16x8 bh = __builtin_bit_cast(bf16x8, eb[chunk * 32 + col]);
            bf16x8 bl = __builtin_bit_cast(bf16x8, eb[1024 + chunk * 32 + col]);
            acc = __builtin_amdgcn_mfma_f32_32x32x16_bf16(ah[s], bh, acc, 0, 0, 0);
            acc = __builtin_amdgcn_mfma_f32_32x32x16_bf16(ah[s], bl, acc, 0, 0, 0);
            acc = __builtin_amdgcn_mfma_f32_32x32x16_bf16(al[s], bh, acc, 0, 0, 0);
        }

        const int code = ct * 32 + col;
        const float c2 = c2s[code];
        #pragma unroll
        for (int r = 0; r < 16; ++r) {
            float sc = fmaf(-2.0f, acc[r], c2);
            if (sc < best[r]) { best2[r] = best[r]; best[r] = sc; bidx[r] = code; }
            else if (sc < best2[r]) { best2[r] = sc; }
        }

        asm volatile("s_waitcnt vmcnt(0)" ::: "memory");   // next tile landed
        __syncthreads();                                    // all readers done + data visible
        cur ^= 1;
    }

    // cross-lane top-2 merge over the 32 code columns (g kept separate: rows differ)
    #pragma unroll
    for (int m = 1; m <= 16; m <<= 1) {
        #pragma unroll
        for (int r = 0; r < 16; ++r) {
            float ov  = __shfl_xor(best[r],  m, 64);
            int   oi  = __shfl_xor(bidx[r],  m, 64);
            float ov2 = __shfl_xor(best2[r], m, 64);
            bool owin = (ov < best[r]) || (ov == best[r] && oi < bidx[r]);
            float loser = owin ? best[r] : ov;
            best2[r] = fminf(fminf(best2[r], ov2), loser);
            if (owin) { best[r] = ov; bidx[r] = oi; }
        }
    }
    if (col == 0) {
        #pragma unroll
        for (int r = 0; r < 16; ++r) {
            int pos = (r & 3) + 8 * (r >> 2) + 4 * g;
            int n = n0 + w * 32 + pos;
            idxout[n] = bidx[r];
            if (best2[r] - best[r] < GAP_TAU) {
                int slot = atomicAdd(flagcnt, 1);
                if (slot < 65536) flaglist[slot] = n;
            }
        }
    }
}

// ---------------------------------------------------------------------------
// K2b: refine flagged rows, replicating the numpy-fp32 reference pipeline.
// (unchanged from the passing rounds)
// ---------------------------------------------------------------------------
__global__ __launch_bounds__(256) void k_refine(const float* __restrict__ x,
                                                const float* __restrict__ w,
                                                const float* __restrict__ bias,
                                                const float* __restrict__ cb,
                                                const int* __restrict__ flaglist,
                                                const int* __restrict__ flagcnt,
                                                int* __restrict__ idxout) {
    __shared__ float xs[256];
    __shared__ float flat[256];
    __shared__ float fn[256];
    __shared__ float sq[256];
    __shared__ float sv[256];
    __shared__ int   si[256];
    __shared__ float bc[2];
    const int t = threadIdx.x;
    int cnt = *flagcnt;
    if (cnt > 65536) cnt = 65536;

    for (int r = blockIdx.x; r < cnt; r += gridDim.x) {
        const int n = flaglist[r];
        const int b = n >> 12, s = n & 4095;
        xs[t] = x[((size_t)b * 256 + t) * 4096 + s];
        __syncthreads();
        {
            const f4* xv4 = (const f4*)xs;
            const f4* wv4 = (const f4*)(w + (size_t)t * 256);
            float a0 = 0.f, a1 = 0.f, a2 = 0.f, a3 = 0.f;
            for (int c4 = 0; c4 < 64; ++c4) {
                f4 xv = xv4[c4];
                f4 wv = wv4[c4];
                a0 = __fadd_rn(a0, __fmul_rn(xv[0], wv[0]));
                a1 = __fadd_rn(a1, __fmul_rn(xv[1], wv[1]));
                a2 = __fadd_rn(a2, __fmul_rn(xv[2], wv[2]));
                a3 = __fadd_rn(a3, __fmul_rn(xv[3], wv[3]));
            }
            float q = __fadd_rn(__fadd_rn(a0, a1), __fadd_rn(a2, a3));
            flat[t] = __fadd_rn(q, bias[t]);
        }
        sq[t] = __fmul_rn(flat[t], flat[t]);
        __syncthreads();
        if (t == 0) bc[0] = fmaxf(__fsqrt_rn(np_sum256(sq)), 1e-12f);
        __syncthreads();
        fn[t] = __fdiv_rn(flat[t], bc[0]);
        __syncthreads();
        sq[t] = __fmul_rn(fn[t], fn[t]);
        __syncthreads();
        if (t == 0) bc[1] = np_sum256(sq);
        __syncthreads();
        const float t1f = bc[1];

        float best = 3.4e38f; int bi = 0x7fffffff;
        #pragma unroll 1
        for (int kq = 0; kq < 4; ++kq) {
            int k = kq * 256 + t;
            const f4* e4 = (const f4*)(cb + (size_t)k * 256);
            double dot = 0.0;
            float hres[2];
            #pragma unroll 1
            for (int h = 0; h < 2; ++h) {
                float rr[8][4];
                #pragma unroll
                for (int j = 0; j < 8; ++j)
                    #pragma unroll
                    for (int l = 0; l < 4; ++l) rr[j][l] = 0.f;
                #pragma unroll 1
                for (int m = 0; m < 4; ++m) {
                    #pragma unroll
                    for (int j = 0; j < 8; ++j) {
                        f4 v = e4[h * 32 + m * 8 + j];
                        #pragma unroll
                        for (int l = 0; l < 4; ++l) {
                            dot += (double)fn[h * 128 + m * 32 + j * 4 + l] * (double)v[l];
                            rr[j][l] = __fadd_rn(rr[j][l], __fmul_rn(v[l], v[l]));
                        }
                    }
                }
                float c[4];
                #pragma unroll
                for (int l = 0; l < 4; ++l) {
                    float t01 = __fadd_rn(rr[0][l], rr[1][l]);
                    float t23 = __fadd_rn(rr[2][l], rr[3][l]);
                    float t45 = __fadd_rn(rr[4][l], rr[5][l]);
                    float t67 = __fadd_rn(rr[6][l], rr[7][l]);
                    c[l] = __fadd_rn(__fadd_rn(t01, t23), __fadd_rn(t45, t67));
                }
                hres[h] = __fadd_rn(__fadd_rn(c[0], c[1]), __fadd_rn(c[2], c[3]));
            }
            float e2f = __fadd_rn(hres[0], hres[1]);
            float gf  = (float)(2.0 * dot);
            float d2  = __fadd_rn(__fsub_rn(t1f, gf), e2f);
            if (d2 < best) { best = d2; bi = k; }
        }
        sv[t] = best; si[t] = bi;
        __syncthreads();
        for (int off = 128; off > 0; off >>= 1) {
            if (t < off) {
                if (sv[t + off] < sv[t] || (sv[t + off] == sv[t] && si[t + off] < si[t])) {
                    sv[t] = sv[t + off]; si[t] = si[t + off];
                }
            }
            __syncthreads();
        }
        if (t == 0) idxout[n] = si[0];
        __syncthreads();
    }
}

// ---------------------------------------------------------------------------
// K3: gather + NHWC->NCHW write.
// ---------------------------------------------------------------------------
__global__ __launch_bounds__(256) void k_gather(const int* __restrict__ idx,
                                                const float* __restrict__ cb,
                                                float* __restrict__ out) {
    const int t = threadIdx.x;
    const int b = blockIdx.x >> 4;
    const int s = ((blockIdx.x & 15) << 8) + t;
    const int n = b * 4096 + s;
    const int k = idx[n];
    const f4* row = (const f4*)(cb + (size_t)k * 256);
    float* ob = out + (size_t)b * 256 * 4096 + s;
    #pragma unroll 8
    for (int d4 = 0; d4 < 64; ++d4) {
        f4 v = row[d4];
        ob[(size_t)(d4 * 4 + 0) * 4096] = v[0];
        ob[(size_t)(d4 * 4 + 1) * 4096] = v[1];
        ob[(size_t)(d4 * 4 + 2) * 4096] = v[2];
        ob[(size_t)(d4 * 4 + 3) * 4096] = v[3];
    }
}

// ---------------------------------------------------------------------------
extern "C" void kernel_launch(void* const* d_in, const int* in_sizes, int n_in,
                              void* d_out, int out_size, void* d_ws, size_t ws_size,
                              hipStream_t stream) {
    const float* x    = (const float*)d_in[0];
    const float* w    = (const float*)d_in[1];
    const float* bias = (const float*)d_in[2];
    const float* cb   = (const float*)d_in[3];
    float* out = (float*)d_out;

    char* ws = (char*)d_ws;
    unsigned short* fh    = (unsigned short*)ws;                  // 33554432 B
    unsigned short* fl    = (unsigned short*)(ws + 33554432);     // 33554432 B
    int*            idx   = (int*)(ws + 67108864);                //   262144 B
    float*          c2s   = (float*)(ws + 67371008);              //     4096 B
    int*            fcnt  = (int*)(ws + 67375104);                //      256 B
    int*            flist = (int*)(ws + 67375360);                //   262144 B
    unsigned short* eh    = (unsigned short*)(ws + 67637504);     //   524288 B (transposed granules)
    unsigned short* el    = (unsigned short*)(ws + 68161792);     //   524288 B

    hipMemsetAsync(fcnt, 0, 4, stream);
    k_c2    <<<4,    256, 0, stream>>>(cb, c2s);
    k_pack  <<<1024, 256, 0, stream>>>(cb, eh, el);
    k_conv  <<<1024, 256, 0, stream>>>(x, w, bias, fh, fl);
    k_dist  <<<256,  512, 0, stream>>>(fh, fl, eh, el, c2s, idx, fcnt, flist);
    k_refine<<<256,  256, 0, stream>>>(x, w, bias, cb, flist, fcnt, idx);
    k_gather<<<256,  256, 0, stream>>>(idx, cb, out);
}